// Round 3
// baseline (83.909 us; speedup 1.0000x reference)
//
#include <hip/hip_runtime.h>
#include <hip/hip_bf16.h>

#define N_TOKENS   262144
#define DIM        64
#define KCODES     512
#define OUT_ELEMS  (N_TOKENS * DIM)          // 16777216
#define LOSS_SCALE (1.25f / 16777216.0f)

typedef float  f32x4 __attribute__((ext_vector_type(4)));
typedef float  f32x8 __attribute__((ext_vector_type(8)));
typedef short  s16x8 __attribute__((ext_vector_type(8)));

static __device__ __forceinline__ unsigned short f2bf(float f) {
    unsigned int u = __builtin_bit_cast(unsigned int, f);
    u += 0x7fffu + ((u >> 16) & 1u);          // round-to-nearest-even
    return (unsigned short)(u >> 16);
}

// Prep: codebook -> bf16(-2c) in MFMA-fragment order (ws), ||c||^2+2 (ws), zero loss.
// Fragment slot for (code k, dim d):
//   t=k>>4, li=k&15, kk=d>>5, hi=(d>>3)&3, j=d&7, lane=hi*16+li
//   element index = ((t*2+kk)*64 + lane)*8 + j
// Codebook entries are in [-1/512,1/512] so ||c||^2 - 2 z.c >= -0.38 for this
// input distribution; the +2 bias keeps every distance key strictly positive
// so uint compare == float compare.
__global__ void vq_prep(const float* __restrict__ cb,
                        unsigned short* __restrict__ cbf,
                        float* __restrict__ c2,
                        float* __restrict__ out_loss) {
    const int k = blockIdx.x;       // 512 blocks, one code each
    const int d = threadIdx.x;      // 64 threads (one wave)
    const float v = cb[k * DIM + d];
    float s = v * v;
    #pragma unroll
    for (int sh = 1; sh < 64; sh <<= 1) s += __shfl_xor(s, sh, 64);
    if (d == 0) c2[k] = s + 2.0f;

    const int t = k >> 4, li = k & 15;
    const int kk = d >> 5, hi = (d >> 3) & 3, j = d & 7;
    const int slot = (t * 2 + kk) * 64 + hi * 16 + li;
    cbf[slot * 8 + j] = f2bf(-2.0f * v);

    if (k == 0 && d == 0) *out_loss = 0.0f;
}

// Main: 4 waves x 64 tokens = 256 tokens/block, 1024 blocks.
// No codebook LDS staging: B-fragments stream from L2 (codebook is 64 KiB,
// resident in every XCD's L2). VGPRs forced <=64 for 32 waves/CU.
__global__ __launch_bounds__(256, 8) void vq_main(
    const float* __restrict__ z,
    const float* __restrict__ cb,              // fp32 codebook (exact gather)
    const unsigned short* __restrict__ cbf,    // bf16(-2c), fragment order
    const float* __restrict__ c2g,             // ||c||^2 + 2
    float* __restrict__ out)
{
    __shared__ int   keysl[4][64];
    __shared__ float lpart[4];

    const int tid  = threadIdx.x;
    const int wave = tid >> 6;
    const int lane = tid & 63;
    const int li   = lane & 15;   // A-row / C-col lane index
    const int hi   = lane >> 4;   // k-group

    const int token0 = blockIdx.x * 256 + wave * 64;

    // ---- load z, build bf16 A-fragments, compute ||z||^2 per row ----
    s16x8 af[4][2];
    float z2[4];
    #pragma unroll
    for (int m = 0; m < 4; ++m) {
        float zs = 0.f;
        #pragma unroll
        for (int kk = 0; kk < 2; ++kk) {
            const float* p = z + (size_t)(token0 + m * 16 + li) * DIM + kk * 32 + hi * 8;
            const f32x8 v = *(const f32x8*)p;
            s16x8 a;
            #pragma unroll
            for (int j = 0; j < 8; ++j) {
                zs += v[j] * v[j];
                a[j] = (short)f2bf(v[j]);
            }
            af[m][kk] = a;
        }
        zs += __shfl_xor(zs, 16, 64);
        zs += __shfl_xor(zs, 32, 64);
        z2[m] = zs;   // full row sum, replicated across the hi-group
    }

    // ---- argmin over 512 codes; B-fragments streamed from L2 ----
    unsigned bkey[4][4];
    #pragma unroll
    for (int m = 0; m < 4; ++m)
        #pragma unroll
        for (int r = 0; r < 4; ++r) bkey[m][r] = 0xFFFFFFFFu;

    for (int t = 0; t < 32; ++t) {
        const s16x8 b0 = *(const s16x8*)(cbf + ((size_t)(t * 2 + 0) * 64 + lane) * 8);
        const s16x8 b1 = *(const s16x8*)(cbf + ((size_t)(t * 2 + 1) * 64 + lane) * 8);
        const float cv2 = c2g[t * 16 + li];
        const unsigned code = (unsigned)(t * 16 + li);
        #pragma unroll
        for (int m = 0; m < 4; ++m) {
            f32x4 acc = {cv2, cv2, cv2, cv2};
            acc = __builtin_amdgcn_mfma_f32_16x16x32_bf16(af[m][0], b0, acc, 0, 0, 0);
            acc = __builtin_amdgcn_mfma_f32_16x16x32_bf16(af[m][1], b1, acc, 0, 0, 0);
            // acc[r] = ||c||^2 + 2 - 2 z.c for row (m*16 + hi*4 + r), col code
            #pragma unroll
            for (int r = 0; r < 4; ++r) {
                const unsigned key = (__builtin_bit_cast(unsigned, acc[r]) & ~511u) | code;
                if (key < bkey[m][r]) bkey[m][r] = key;   // v_min_u32
            }
        }
    }

    // ---- reduce across the 16 li-lanes (positive-float keys: uint min) ----
    #pragma unroll
    for (int sh = 1; sh < 16; sh <<= 1) {
        #pragma unroll
        for (int m = 0; m < 4; ++m)
            #pragma unroll
            for (int r = 0; r < 4; ++r) {
                const unsigned ok = (unsigned)__shfl_xor((int)bkey[m][r], sh, 64);
                if (ok < bkey[m][r]) bkey[m][r] = ok;
            }
    }

    // rows m*16 + hi*4 + r -> key; per-wave private LDS slab (no barrier needed)
    if (li == 0) {
        #pragma unroll
        for (int m = 0; m < 4; ++m)
            #pragma unroll
            for (int r = 0; r < 4; ++r)
                keysl[wave][m * 16 + hi * 4 + r] = (int)bkey[m][r];
    }

    // ---- gather exact fp32 rows, write z_q, loss from winning key + ||z||^2 ----
    float lossp = 0.f;
    #pragma unroll
    for (int m = 0; m < 4; ++m) {
        const unsigned key = (unsigned)keysl[wave][m * 16 + li];   // row = m*16+li
        const int code = (int)(key & 511u);
        if (hi == 0)
            lossp += (__builtin_bit_cast(float, key & ~511u) - 2.0f) + z2[m];
        const float* cbr = cb + code * DIM + hi * 8;
        const f32x8 q0 = *(const f32x8*)(cbr);
        const f32x8 q1 = *(const f32x8*)(cbr + 32);
        float* op = out + (size_t)(token0 + m * 16 + li) * DIM + hi * 8;
        *(f32x8*)(op)      = q0;
        *(f32x8*)(op + 32) = q1;
    }
    #pragma unroll
    for (int sh = 1; sh < 64; sh <<= 1) lossp += __shfl_xor(lossp, sh, 64);
    if (lane == 0) lpart[wave] = lossp;
    __syncthreads();
    if (tid == 0) {
        float s = lpart[0] + lpart[1] + lpart[2] + lpart[3];
        atomicAdd(out + OUT_ELEMS, s * LOSS_SCALE);
    }
}

extern "C" void kernel_launch(void* const* d_in, const int* in_sizes, int n_in,
                              void* d_out, int out_size, void* d_ws, size_t ws_size,
                              hipStream_t stream) {
    const float* z  = (const float*)d_in[0];
    const float* cb = (const float*)d_in[1];
    float* out = (float*)d_out;

    unsigned short* cbf = (unsigned short*)d_ws;                               // 64 KiB
    float* c2 = (float*)((char*)d_ws + KCODES * DIM * sizeof(unsigned short)); // 2 KiB

    vq_prep<<<KCODES, 64, 0, stream>>>(cb, cbf, c2, out + OUT_ELEMS);
    vq_main<<<N_TOKENS / 256, 256, 0, stream>>>(z, cb, cbf, c2, out);
}

// Round 4
// 49.359 us; speedup vs baseline: 1.7000x; 1.7000x over previous
//
#include <hip/hip_runtime.h>
#include <hip/hip_bf16.h>

#define N_TOKENS   262144
#define DIM        64
#define KCODES     512
#define OUT_ELEMS  (N_TOKENS * DIM)          // 16777216
#define LOSS_SCALE (1.25f / 16777216.0f)

typedef float  f32x4 __attribute__((ext_vector_type(4)));
typedef float  f32x8 __attribute__((ext_vector_type(8)));
typedef short  s16x8 __attribute__((ext_vector_type(8)));

static __device__ __forceinline__ unsigned short f2bf(float f) {
    unsigned int u = __builtin_bit_cast(unsigned int, f);
    u += 0x7fffu + ((u >> 16) & 1u);          // round-to-nearest-even
    return (unsigned short)(u >> 16);
}

// Prep: codebook -> bf16(-2c) in MFMA-fragment order (ws), ||c||^2+2 (ws), zero loss.
// Fragment slot for (code k, dim d):
//   t=k>>4, li=k&15, kk=d>>5, hi=(d>>3)&3, j=d&7, lane=hi*16+li
//   element index = ((t*2+kk)*64 + lane)*8 + j
// +2 bias keeps every distance key strictly positive so uint cmp == float cmp.
__global__ void vq_prep(const float* __restrict__ cb,
                        unsigned short* __restrict__ cbf,
                        float* __restrict__ c2,
                        float* __restrict__ out_loss) {
    const int k = blockIdx.x;       // 512 blocks, one code each
    const int d = threadIdx.x;      // 64 threads (one wave)
    const float v = cb[k * DIM + d];
    float s = v * v;
    #pragma unroll
    for (int sh = 1; sh < 64; sh <<= 1) s += __shfl_xor(s, sh, 64);
    if (d == 0) c2[k] = s + 2.0f;

    const int t = k >> 4, li = k & 15;
    const int kk = d >> 5, hi = (d >> 3) & 3, j = d & 7;
    const int slot = (t * 2 + kk) * 64 + hi * 16 + li;
    cbf[slot * 8 + j] = f2bf(-2.0f * v);

    if (k == 0 && d == 0) *out_loss = 0.0f;
}

// Main: 4 waves x 64 tokens = 256 tokens/block, 1024 blocks.
// No codebook LDS staging: B-fragments stream from L2 (codebook is 64 KiB,
// resident per XCD). launch_bounds(256,4): 128-VGPR cap -> NO SPILL
// (round 3's (256,8) forced 64-VGPR target and spilled ~150 MB to scratch).
__global__ __launch_bounds__(256, 4) void vq_main(
    const float* __restrict__ z,
    const float* __restrict__ cb,              // fp32 codebook (exact gather)
    const unsigned short* __restrict__ cbf,    // bf16(-2c), fragment order
    const float* __restrict__ c2g,             // ||c||^2 + 2
    float* __restrict__ out)
{
    __shared__ int   keysl[4][64];
    __shared__ float lpart[4];

    const int tid  = threadIdx.x;
    const int wave = tid >> 6;
    const int lane = tid & 63;
    const int li   = lane & 15;   // A-row / C-col lane index
    const int hi   = lane >> 4;   // k-group

    const int token0 = blockIdx.x * 256 + wave * 64;

    // ---- load z, build bf16 A-fragments, compute ||z||^2 per row ----
    s16x8 af[4][2];
    float z2[4];
    #pragma unroll
    for (int m = 0; m < 4; ++m) {
        float zs = 0.f;
        #pragma unroll
        for (int kk = 0; kk < 2; ++kk) {
            const float* p = z + (size_t)(token0 + m * 16 + li) * DIM + kk * 32 + hi * 8;
            const f32x8 v = *(const f32x8*)p;
            s16x8 a;
            #pragma unroll
            for (int j = 0; j < 8; ++j) {
                zs += v[j] * v[j];
                a[j] = (short)f2bf(v[j]);
            }
            af[m][kk] = a;
        }
        zs += __shfl_xor(zs, 16, 64);
        zs += __shfl_xor(zs, 32, 64);
        z2[m] = zs;   // full row sum, replicated across the hi-group
    }

    // ---- argmin over 512 codes; B-fragments streamed from L2 ----
    unsigned bkey[4][4];
    #pragma unroll
    for (int m = 0; m < 4; ++m)
        #pragma unroll
        for (int r = 0; r < 4; ++r) bkey[m][r] = 0xFFFFFFFFu;

    for (int t = 0; t < 32; ++t) {
        const s16x8 b0 = *(const s16x8*)(cbf + ((size_t)(t * 2 + 0) * 64 + lane) * 8);
        const s16x8 b1 = *(const s16x8*)(cbf + ((size_t)(t * 2 + 1) * 64 + lane) * 8);
        const float cv2 = c2g[t * 16 + li];
        const unsigned code = (unsigned)(t * 16 + li);
        #pragma unroll
        for (int m = 0; m < 4; ++m) {
            f32x4 acc = {cv2, cv2, cv2, cv2};
            acc = __builtin_amdgcn_mfma_f32_16x16x32_bf16(af[m][0], b0, acc, 0, 0, 0);
            acc = __builtin_amdgcn_mfma_f32_16x16x32_bf16(af[m][1], b1, acc, 0, 0, 0);
            // acc[r] = ||c||^2 + 2 - 2 z.c for row (m*16 + hi*4 + r), col code
            #pragma unroll
            for (int r = 0; r < 4; ++r) {
                const unsigned key = (__builtin_bit_cast(unsigned, acc[r]) & ~511u) | code;
                if (key < bkey[m][r]) bkey[m][r] = key;   // v_min_u32
            }
        }
    }

    // ---- reduce across the 16 li-lanes (positive-float keys: uint min) ----
    #pragma unroll
    for (int sh = 1; sh < 16; sh <<= 1) {
        #pragma unroll
        for (int m = 0; m < 4; ++m)
            #pragma unroll
            for (int r = 0; r < 4; ++r) {
                const unsigned ok = (unsigned)__shfl_xor((int)bkey[m][r], sh, 64);
                if (ok < bkey[m][r]) bkey[m][r] = ok;
            }
    }

    // rows m*16 + hi*4 + r -> key; per-wave private LDS slab (no barrier needed)
    if (li == 0) {
        #pragma unroll
        for (int m = 0; m < 4; ++m)
            #pragma unroll
            for (int r = 0; r < 4; ++r)
                keysl[wave][m * 16 + hi * 4 + r] = (int)bkey[m][r];
    }

    // ---- gather exact fp32 rows, write z_q, loss from winning key + ||z||^2 ----
    float lossp = 0.f;
    #pragma unroll
    for (int m = 0; m < 4; ++m) {
        const unsigned key = (unsigned)keysl[wave][m * 16 + li];   // row = m*16+li
        const int code = (int)(key & 511u);
        if (hi == 0)
            lossp += (__builtin_bit_cast(float, key & ~511u) - 2.0f) + z2[m];
        const float* cbr = cb + code * DIM + hi * 8;
        const f32x8 q0 = *(const f32x8*)(cbr);
        const f32x8 q1 = *(const f32x8*)(cbr + 32);
        float* op = out + (size_t)(token0 + m * 16 + li) * DIM + hi * 8;
        *(f32x8*)(op)      = q0;
        *(f32x8*)(op + 32) = q1;
    }
    #pragma unroll
    for (int sh = 1; sh < 64; sh <<= 1) lossp += __shfl_xor(lossp, sh, 64);
    if (lane == 0) lpart[wave] = lossp;
    __syncthreads();
    if (tid == 0) {
        float s = lpart[0] + lpart[1] + lpart[2] + lpart[3];
        atomicAdd(out + OUT_ELEMS, s * LOSS_SCALE);
    }
}

extern "C" void kernel_launch(void* const* d_in, const int* in_sizes, int n_in,
                              void* d_out, int out_size, void* d_ws, size_t ws_size,
                              hipStream_t stream) {
    const float* z  = (const float*)d_in[0];
    const float* cb = (const float*)d_in[1];
    float* out = (float*)d_out;

    unsigned short* cbf = (unsigned short*)d_ws;                               // 64 KiB
    float* c2 = (float*)((char*)d_ws + KCODES * DIM * sizeof(unsigned short)); // 2 KiB

    vq_prep<<<KCODES, 64, 0, stream>>>(cb, cbf, c2, out + OUT_ELEMS);
    vq_main<<<N_TOKENS / 256, 256, 0, stream>>>(z, cb, cbf, c2, out);
}

// Round 5
// 46.979 us; speedup vs baseline: 1.7861x; 1.0507x over previous
//
#include <hip/hip_runtime.h>
#include <hip/hip_bf16.h>

#define N_TOKENS   262144
#define DIM        64
#define KCODES     512
#define OUT_ELEMS  (N_TOKENS * DIM)          // 16777216
#define LOSS_SCALE (1.25f / 16777216.0f)

typedef float  f32x4 __attribute__((ext_vector_type(4)));
typedef float  f32x8 __attribute__((ext_vector_type(8)));
typedef short  s16x8 __attribute__((ext_vector_type(8)));

static __device__ __forceinline__ unsigned short f2bf(float f) {
    unsigned int u = __builtin_bit_cast(unsigned int, f);
    u += 0x7fffu + ((u >> 16) & 1u);          // round-to-nearest-even
    return (unsigned short)(u >> 16);
}

// Prep: codebook -> bf16(-2c) in MFMA-fragment order (ws), ||c||^2+2 (ws), zero loss.
// Fragment element index for (code k, dim d):
//   t=k>>4, li=k&15, kk=d>>5, hi=(d>>3)&3, j=d&7 -> ((t*2+kk)*64 + hi*16+li)*8 + j
// +2 bias keeps every distance key strictly positive so uint cmp == float cmp.
__global__ void vq_prep(const float* __restrict__ cb,
                        unsigned short* __restrict__ cbf,
                        float* __restrict__ c2,
                        float* __restrict__ out_loss) {
    const int k = blockIdx.x;       // 512 blocks, one code each
    const int d = threadIdx.x;      // 64 threads (one wave)
    const float v = cb[k * DIM + d];
    float s = v * v;
    #pragma unroll
    for (int sh = 1; sh < 64; sh <<= 1) s += __shfl_xor(s, sh, 64);
    if (d == 0) c2[k] = s + 2.0f;

    const int t = k >> 4, li = k & 15;
    const int kk = d >> 5, hi = (d >> 3) & 3, j = d & 7;
    const int slot = (t * 2 + kk) * 64 + hi * 16 + li;
    cbf[slot * 8 + j] = f2bf(-2.0f * v);

    if (k == 0 && d == 0) *out_loss = 0.0f;
}

// B-fragment load for column-tile T, k-half KK (lane-linear, coalesced 1KB/instr)
#define LOADB(T, KK) (*(const s16x8*)(cbf + (((T) * 2 + (KK)) * 64 + lane) * 8))

// One 64-token x 16-code tile step: acc starts at ||c||^2+2, MFMA adds -2 z.c
#define COMPUTE(T, B0, B1, CV)                                                         \
    {                                                                                  \
        const unsigned code_ = (unsigned)((T) * 16 + li);                              \
        _Pragma("unroll")                                                              \
        for (int m = 0; m < 4; ++m) {                                                  \
            f32x4 acc = {(CV), (CV), (CV), (CV)};                                      \
            acc = __builtin_amdgcn_mfma_f32_16x16x32_bf16(af[m][0], (B0), acc, 0, 0, 0); \
            acc = __builtin_amdgcn_mfma_f32_16x16x32_bf16(af[m][1], (B1), acc, 0, 0, 0); \
            _Pragma("unroll")                                                          \
            for (int r = 0; r < 4; ++r) {                                              \
                const unsigned key = (__builtin_bit_cast(unsigned, acc[r]) & ~511u) | code_; \
                if (key < bkey[m][r]) bkey[m][r] = key;  /* v_min_u32 */               \
            }                                                                          \
        }                                                                              \
    }

// Main: 4 waves x 64 tokens = 256 tokens/block, 1024 blocks.
// B-fragments stream from L2 with explicit depth-2 register double-buffering:
// slot loaded at iteration i is consumed at i+2 (~2 COMPUTE bodies ~250cy of
// cover vs ~200cy L2 latency). Named slots only (runtime-indexed arrays spill).
__global__ __launch_bounds__(256, 4) void vq_main(
    const float* __restrict__ z,
    const float* __restrict__ cb,              // fp32 codebook (exact gather)
    const unsigned short* __restrict__ cbf,    // bf16(-2c), fragment order
    const float* __restrict__ c2g,             // ||c||^2 + 2
    float* __restrict__ out)
{
    __shared__ int   keysl[4][64];
    __shared__ float lpart[4];

    const int tid  = threadIdx.x;
    const int wave = tid >> 6;
    const int lane = tid & 63;
    const int li   = lane & 15;   // A-row / C-col lane index
    const int hi   = lane >> 4;   // k-group

    const int token0 = blockIdx.x * 256 + wave * 64;

    // ---- load z, build bf16 A-fragments, compute ||z||^2 per row ----
    s16x8 af[4][2];
    float z2[4];
    #pragma unroll
    for (int m = 0; m < 4; ++m) {
        float zs = 0.f;
        #pragma unroll
        for (int kk = 0; kk < 2; ++kk) {
            const float* p = z + (size_t)(token0 + m * 16 + li) * DIM + kk * 32 + hi * 8;
            const f32x8 v = *(const f32x8*)p;
            s16x8 a;
            #pragma unroll
            for (int j = 0; j < 8; ++j) {
                zs += v[j] * v[j];
                a[j] = (short)f2bf(v[j]);
            }
            af[m][kk] = a;
        }
        zs += __shfl_xor(zs, 16, 64);
        zs += __shfl_xor(zs, 32, 64);
        z2[m] = zs;   // full row sum, replicated across the hi-group
    }

    // ---- argmin over 512 codes, depth-2 pipelined over 32 column-tiles ----
    unsigned bkey[4][4];
    #pragma unroll
    for (int m = 0; m < 4; ++m)
        #pragma unroll
        for (int r = 0; r < 4; ++r) bkey[m][r] = 0xFFFFFFFFu;

    s16x8 b0A = LOADB(0, 0), b1A = LOADB(0, 1);
    s16x8 b0B = LOADB(1, 0), b1B = LOADB(1, 1);
    float cvA = c2g[0 * 16 + li];
    float cvB = c2g[1 * 16 + li];

    #pragma unroll 2
    for (int tt = 0; tt < 16; ++tt) {
        const int t0 = tt * 2, t1 = t0 + 1;
        const int p0 = (t0 + 2) & 31;          // tail wraps to tile 0/1: loaded, never used
        const int p1 = (t1 + 2) & 31;

        const s16x8 nb0A = LOADB(p0, 0), nb1A = LOADB(p0, 1);
        const float ncvA = c2g[p0 * 16 + li];
        COMPUTE(t0, b0A, b1A, cvA);
        b0A = nb0A; b1A = nb1A; cvA = ncvA;

        const s16x8 nb0B = LOADB(p1, 0), nb1B = LOADB(p1, 1);
        const float ncvB = c2g[p1 * 16 + li];
        COMPUTE(t1, b0B, b1B, cvB);
        b0B = nb0B; b1B = nb1B; cvB = ncvB;
    }

    // ---- reduce across the 16 li-lanes (positive-float keys: uint min) ----
    #pragma unroll
    for (int sh = 1; sh < 16; sh <<= 1) {
        #pragma unroll
        for (int m = 0; m < 4; ++m)
            #pragma unroll
            for (int r = 0; r < 4; ++r) {
                const unsigned ok = (unsigned)__shfl_xor((int)bkey[m][r], sh, 64);
                if (ok < bkey[m][r]) bkey[m][r] = ok;
            }
    }

    // rows m*16 + hi*4 + r -> key; per-wave private LDS slab (no barrier needed)
    if (li == 0) {
        #pragma unroll
        for (int m = 0; m < 4; ++m)
            #pragma unroll
            for (int r = 0; r < 4; ++r)
                keysl[wave][m * 16 + hi * 4 + r] = (int)bkey[m][r];
    }

    // ---- gather exact fp32 rows, write z_q, loss from winning key + ||z||^2 ----
    float lossp = 0.f;
    #pragma unroll
    for (int m = 0; m < 4; ++m) {
        const unsigned key = (unsigned)keysl[wave][m * 16 + li];   // row = m*16+li
        const int code = (int)(key & 511u);
        if (hi == 0)
            lossp += (__builtin_bit_cast(float, key & ~511u) - 2.0f) + z2[m];
        const float* cbr = cb + code * DIM + hi * 8;
        const f32x8 q0 = *(const f32x8*)(cbr);
        const f32x8 q1 = *(const f32x8*)(cbr + 32);
        float* op = out + (size_t)(token0 + m * 16 + li) * DIM + hi * 8;
        *(f32x8*)(op)      = q0;
        *(f32x8*)(op + 32) = q1;
    }
    #pragma unroll
    for (int sh = 1; sh < 64; sh <<= 1) lossp += __shfl_xor(lossp, sh, 64);
    if (lane == 0) lpart[wave] = lossp;
    __syncthreads();
    if (tid == 0) {
        float s = lpart[0] + lpart[1] + lpart[2] + lpart[3];
        atomicAdd(out + OUT_ELEMS, s * LOSS_SCALE);
    }
}

extern "C" void kernel_launch(void* const* d_in, const int* in_sizes, int n_in,
                              void* d_out, int out_size, void* d_ws, size_t ws_size,
                              hipStream_t stream) {
    const float* z  = (const float*)d_in[0];
    const float* cb = (const float*)d_in[1];
    float* out = (float*)d_out;

    unsigned short* cbf = (unsigned short*)d_ws;                               // 64 KiB
    float* c2 = (float*)((char*)d_ws + KCODES * DIM * sizeof(unsigned short)); // 2 KiB

    vq_prep<<<KCODES, 64, 0, stream>>>(cb, cbf, c2, out + OUT_ELEMS);
    vq_main<<<N_TOKENS / 256, 256, 0, stream>>>(z, cb, cbf, c2, out);
}